// Round 1
// baseline (1106.429 us; speedup 1.0000x reference)
//
#include <hip/hip_runtime.h>

// NCM: 32 nodes, roots 0..3 (in=16), inner 4..31 (in=80: 4 thresholded parents + exo).
// One block = 64 batch elements, walks all 32 nodes sequentially (deps are
// intra-batch-element only). Wave g (of 4) computes hidden/output slice
// [16g,16g+16) -> weight addresses wave-uniform -> scalar loads (s_load) and
// v_fmac with SGPR weight operand. Activations transposed in LDS [feat][lane]
// (lane-stride-1, conflict-free). Parent threshold bits in a 4-slot LDS ring.

#define BT 64

__global__ __launch_bounds__(256, 2) void ncm_kernel(
    const float* __restrict__ u,
    const float* __restrict__ w_r1, const float* __restrict__ b_r1,
    const float* __restrict__ w_r2, const float* __restrict__ b_r2,
    const float* __restrict__ w_r3, const float* __restrict__ b_r3,
    const float* __restrict__ w_i1, const float* __restrict__ b_i1,
    const float* __restrict__ w_i2, const float* __restrict__ b_i2,
    const float* __restrict__ w_i3, const float* __restrict__ b_i3,
    float* __restrict__ out)
{
    __shared__ float Xb[4][16][BT];   // parent bit ring, slot = node & 3
    __shared__ float Xu[16][BT];      // current node's exogenous inputs (transposed)
    __shared__ float H1[64][BT];
    __shared__ float H2[64][BT];

    const int tid  = threadIdx.x;
    const int lane = tid & 63;                                  // batch sub-index
    const int wv   = __builtin_amdgcn_readfirstlane(tid >> 6);  // wave id 0..3 (uniform)
    const long eg  = (long)blockIdx.x * BT + lane;              // global batch element
    const float* u_row   = u   + eg * 512;
    float*       out_row = out + eg * 512;

    for (int i = 0; i < 32; ++i) {
        // stage this node's exo inputs (read early, overlaps prior sync)
        float4 uv = *(const float4*)(u_row + i * 16 + wv * 4);
        __syncthreads();   // prior node fully done (Xb slot written)
        Xu[wv * 4 + 0][lane] = uv.x;
        Xu[wv * 4 + 1][lane] = uv.y;
        Xu[wv * 4 + 2][lane] = uv.z;
        Xu[wv * 4 + 3][lane] = uv.w;
        __syncthreads();   // Xu visible to all waves

        float acc[16];

        // ---- layer 1 ----
        if (i < 4) {
            const float* W1 = w_r1 + i * (16 * 64) + wv * 16;   // [k][o], stride 64
            const float* B1 = b_r1 + i * 64 + wv * 16;
            #pragma unroll
            for (int o = 0; o < 16; ++o) acc[o] = B1[o];
            #pragma unroll
            for (int k = 0; k < 16; ++k) {
                float x = Xu[k][lane];
                #pragma unroll
                for (int o = 0; o < 16; ++o)
                    acc[o] = fmaf(x, W1[k * 64 + o], acc[o]);
            }
        } else {
            const int j = i - 4;
            const float* W1 = w_i1 + (long)j * (80 * 64) + wv * 16;
            const float* B1 = b_i1 + j * 64 + wv * 16;
            #pragma unroll
            for (int o = 0; o < 16; ++o) acc[o] = B1[o];
            // 4 thresholded parents: parent p = i-4+pp lives in ring slot (i+pp)&3
            for (int pp = 0; pp < 4; ++pp) {
                const int slot = (i + pp) & 3;
                const float* W1p = W1 + pp * (16 * 64);
                #pragma unroll
                for (int d = 0; d < 16; ++d) {
                    float x = Xb[slot][d][lane];
                    #pragma unroll
                    for (int o = 0; o < 16; ++o)
                        acc[o] = fmaf(x, W1p[d * 64 + o], acc[o]);
                }
            }
            const float* W1u = W1 + 64 * 64;  // exo part, k = 64..79
            #pragma unroll
            for (int d = 0; d < 16; ++d) {
                float x = Xu[d][lane];
                #pragma unroll
                for (int o = 0; o < 16; ++o)
                    acc[o] = fmaf(x, W1u[d * 64 + o], acc[o]);
            }
        }
        #pragma unroll
        for (int o = 0; o < 16; ++o)
            H1[wv * 16 + o][lane] = fmaxf(acc[o], 0.0f);
        __syncthreads();

        // ---- layer 2 ----
        const float* W2 = (i < 4) ? (w_r2 + i * (64 * 64) + wv * 16)
                                  : (w_i2 + (long)(i - 4) * (64 * 64) + wv * 16);
        const float* B2 = (i < 4) ? (b_r2 + i * 64 + wv * 16)
                                  : (b_i2 + (i - 4) * 64 + wv * 16);
        #pragma unroll
        for (int o = 0; o < 16; ++o) acc[o] = B2[o];
        #pragma unroll 16
        for (int k = 0; k < 64; ++k) {
            float x = H1[k][lane];
            #pragma unroll
            for (int o = 0; o < 16; ++o)
                acc[o] = fmaf(x, W2[k * 64 + o], acc[o]);
        }
        #pragma unroll
        for (int o = 0; o < 16; ++o)
            H2[wv * 16 + o][lane] = fmaxf(acc[o], 0.0f);
        __syncthreads();

        // ---- layer 3: 4 outputs per wave ----
        const float* W3 = (i < 4) ? (w_r3 + i * (64 * 16) + wv * 4)
                                  : (w_i3 + (long)(i - 4) * (64 * 16) + wv * 4);
        const float* B3 = (i < 4) ? (b_r3 + i * 16 + wv * 4)
                                  : (b_i3 + (i - 4) * 16 + wv * 4);
        float v0 = B3[0], v1 = B3[1], v2 = B3[2], v3 = B3[3];
        #pragma unroll 16
        for (int k = 0; k < 64; ++k) {
            float x = H2[k][lane];
            v0 = fmaf(x, W3[k * 16 + 0], v0);
            v1 = fmaf(x, W3[k * 16 + 1], v1);
            v2 = fmaf(x, W3[k * 16 + 2], v2);
            v3 = fmaf(x, W3[k * 16 + 3], v3);
        }
        float4 vo; vo.x = v0; vo.y = v1; vo.z = v2; vo.w = v3;
        *(float4*)(out_row + i * 16 + wv * 4) = vo;   // raw logits out (fp32)
        const int slot = i & 3;                        // this node's ring slot
        Xb[slot][wv * 4 + 0][lane] = (v0 > 0.5f) ? 1.0f : 0.0f;
        Xb[slot][wv * 4 + 1][lane] = (v1 > 0.5f) ? 1.0f : 0.0f;
        Xb[slot][wv * 4 + 2][lane] = (v2 > 0.5f) ? 1.0f : 0.0f;
        Xb[slot][wv * 4 + 3][lane] = (v3 > 0.5f) ? 1.0f : 0.0f;
        // loop-top __syncthreads protects the ring slot for the next node
    }
}

extern "C" void kernel_launch(void* const* d_in, const int* in_sizes, int n_in,
                              void* d_out, int out_size, void* d_ws, size_t ws_size,
                              hipStream_t stream) {
    const float* u    = (const float*)d_in[0];
    const float* w_r1 = (const float*)d_in[1];
    const float* b_r1 = (const float*)d_in[2];
    const float* w_r2 = (const float*)d_in[3];
    const float* b_r2 = (const float*)d_in[4];
    const float* w_r3 = (const float*)d_in[5];
    const float* b_r3 = (const float*)d_in[6];
    const float* w_i1 = (const float*)d_in[7];
    const float* b_i1 = (const float*)d_in[8];
    const float* w_i2 = (const float*)d_in[9];
    const float* b_i2 = (const float*)d_in[10];
    const float* w_i3 = (const float*)d_in[11];
    const float* b_i3 = (const float*)d_in[12];
    float* out = (float*)d_out;

    ncm_kernel<<<dim3(512), dim3(256), 0, stream>>>(
        u, w_r1, b_r1, w_r2, b_r2, w_r3, b_r3,
        w_i1, b_i1, w_i2, b_i2, w_i3, b_i3, out);
}

// Round 3
// 334.634 us; speedup vs baseline: 3.3064x; 3.3064x over previous
//
#include <hip/hip_runtime.h>

// NCM via bf16-split MFMA.
// x = xh+xm+xl (RNE splits), w = wh+wm+wl (pre-split into d_ws by prep kernel).
// Products kept: hh, hm, mh, mm, hl, lh, ml, lm (all >= 2^-24 rel); dropped
// terms (ll, split residual) ~2^-32/2^-25 -> below fp32 accumulation rounding
// -> fp32-equivalent accuracy -> threshold bits (V > 0.5) match fp32 ref.
// Parent bits are exact in bf16 (0/1) -> parent K-region needs only 3 products.
//
// Block = 64 batch elements, 4 waves, walks 32 nodes sequentially.
// L1/L2: wave w owns output feats [16w,16w+16) (N-tile), all 4 M-tiles.
// L3:    wave w owns M-tile w (elems 16w..16w+15), N=16.
// Activations pre-split in LDS as bf16 [elem][feat] so every A-fragment is one
// ds_read_b128. Weights stream from d_ws (L2-resident) as b128 global loads.

#define BT 64

typedef __attribute__((ext_vector_type(8))) short bf16x8;
typedef __attribute__((ext_vector_type(4))) float f32x4;
#define MFMA16 __builtin_amdgcn_mfma_f32_16x16x32_bf16

// ws layout (u16 units), per node i (stride 33792):
//   W1' [3][64 n][96 k]  @ 0      (k 0..63 parents, 64..79 exo, 80..95 zero)
//   W2' [3][64 n][64 k]  @ 18432
//   W3' [3][16 n][64 k]  @ 30720
#define NODE_STRIDE 33792
#define W1_SPLIT    6144
#define W2_OFF      18432
#define W2_SPLIT    4096
#define W3_OFF      30720
#define W3_SPLIT    1024

__device__ inline unsigned short bf16_rne(float x) {
    unsigned u = __float_as_uint(x);
    u += 0x7fffu + ((u >> 16) & 1u);
    return (unsigned short)(u >> 16);
}
__device__ inline float bf16_tof(unsigned short h) {
    return __uint_as_float(((unsigned)h) << 16);
}
__device__ inline void split3(float x, unsigned short& h, unsigned short& m,
                              unsigned short& l) {
    h = bf16_rne(x);
    float r = x - bf16_tof(h);      // exact (Sterbenz)
    m = bf16_rne(r);
    float r2 = r - bf16_tof(m);     // exact
    l = bf16_rne(r2);
}

// ---------------- prep: split weights into ws ----------------
#define PER_NODE_ITEMS (64 * 96 + 64 * 64 + 16 * 64)  // 11264

__global__ void prep_weights(const float* __restrict__ w_r1,
                             const float* __restrict__ w_r2,
                             const float* __restrict__ w_r3,
                             const float* __restrict__ w_i1,
                             const float* __restrict__ w_i2,
                             const float* __restrict__ w_i3,
                             unsigned short* __restrict__ ws) {
    int tid = blockIdx.x * 256 + threadIdx.x;
    if (tid >= 32 * PER_NODE_ITEMS) return;
    int node = tid / PER_NODE_ITEMS;
    int r = tid - node * PER_NODE_ITEMS;
    int off, stride;
    float wv = 0.0f;
    if (r < 6144) {                       // W1': n,k in [64][96]
        int n = r / 96, k = r - n * 96;
        if (k < 64) {
            wv = (node >= 4) ? w_i1[((node - 4) * 80 + k) * 64 + n] : 0.0f;
        } else if (k < 80) {
            wv = (node < 4) ? w_r1[(node * 16 + (k - 64)) * 64 + n]
                            : w_i1[((node - 4) * 80 + k) * 64 + n];
        } // else zero pad
        off = n * 96 + k; stride = W1_SPLIT;
    } else if (r < 10240) {               // W2': [64][64]
        int r2 = r - 6144;
        int n = r2 >> 6, k = r2 & 63;
        wv = (node < 4) ? w_r2[(node * 64 + k) * 64 + n]
                        : w_i2[((node - 4) * 64 + k) * 64 + n];
        off = W2_OFF + n * 64 + k; stride = W2_SPLIT;
    } else {                              // W3': [16][64]
        int r3 = r - 10240;
        int n = r3 >> 6, k = r3 & 63;
        wv = (node < 4) ? w_r3[(node * 64 + k) * 16 + n]
                        : w_i3[((node - 4) * 64 + k) * 16 + n];
        off = W3_OFF + n * 64 + k; stride = W3_SPLIT;
    }
    unsigned short h, m, l;
    split3(wv, h, m, l);
    unsigned short* base = ws + node * NODE_STRIDE;
    base[off] = h;
    base[off + stride] = m;
    base[off + 2 * stride] = l;
}

// ---------------- main kernel ----------------
__global__ __launch_bounds__(256, 2) void ncm_mfma(
    const float* __restrict__ u,
    const unsigned short* __restrict__ ws,
    const float* __restrict__ b_r1, const float* __restrict__ b_r2,
    const float* __restrict__ b_r3, const float* __restrict__ b_i1,
    const float* __restrict__ b_i2, const float* __restrict__ b_i3,
    float* __restrict__ out)
{
    __shared__ __align__(16) unsigned short ring[4][64][24]; // parent bits (bf16 0/1)
    __shared__ __align__(16) unsigned short xu[3][64][32];   // exo splits (16..31 zero)
    __shared__ __align__(16) unsigned short h1s[3][64][72];
    __shared__ __align__(16) unsigned short h2s[3][64][72];

    const int tid = threadIdx.x;
    const int l   = tid & 63;
    const int w   = tid >> 6;     // wave 0..3
    const int lr  = l & 15;       // tile row (A) / col (B,C)
    const int lq  = l >> 4;       // quad 0..3

    for (int z = tid; z < 4 * 64 * 24; z += 256) ((unsigned short*)ring)[z] = 0;
    for (int z = tid; z < 3 * 64 * 32; z += 256) ((unsigned short*)xu)[z] = 0;

    const long eg = (long)blockIdx.x * BT;
    const float* u_blk = u + eg * 512;
    const int n1 = 16 * w + lr;   // this wave's output feature (L1/L2)

    for (int i = 0; i < 32; ++i) {
        __syncthreads();  // prev node fully done (also covers zero-init)

        // ---- stage exo inputs: elem = l, feats 4w..4w+3 ----
        float4 uv = *(const float4*)(u_blk + (long)l * 512 + i * 16 + w * 4);
        {
            unsigned short h0, m0, l0, h1, m1, l1, h2, m2, l2, h3, m3, l3;
            split3(uv.x, h0, m0, l0); split3(uv.y, h1, m1, l1);
            split3(uv.z, h2, m2, l2); split3(uv.w, h3, m3, l3);
            ushort4 vh = make_ushort4(h0, h1, h2, h3);
            ushort4 vm = make_ushort4(m0, m1, m2, m3);
            ushort4 vl = make_ushort4(l0, l1, l2, l3);
            *(ushort4*)&xu[0][l][4 * w] = vh;
            *(ushort4*)&xu[1][l][4 * w] = vm;
            *(ushort4*)&xu[2][l][4 * w] = vl;
        }
        __syncthreads();

        const unsigned short* Wn = ws + i * NODE_STRIDE;

        // ======== L1: wave = N-tile, C = [64 elem][16 feat] ========
        f32x4 acc[4] = {{0,0,0,0},{0,0,0,0},{0,0,0,0},{0,0,0,0}};
        {
            if (i >= 4) {
                #pragma unroll
                for (int k0 = 0; k0 < 64; k0 += 32) {
                    const int f = k0 + lq * 8;            // parent-region k base
                    const int slot = (i + (f >> 4)) & 3;  // ring slot of that parent
                    bf16x8 wb0 = *(const bf16x8*)(Wn + 0 * W1_SPLIT + n1 * 96 + f);
                    bf16x8 wb1 = *(const bf16x8*)(Wn + 1 * W1_SPLIT + n1 * 96 + f);
                    bf16x8 wb2 = *(const bf16x8*)(Wn + 2 * W1_SPLIT + n1 * 96 + f);
                    #pragma unroll
                    for (int m = 0; m < 4; ++m) {
                        bf16x8 ab = *(const bf16x8*)&ring[slot][m * 16 + lr][f & 15];
                        acc[m] = MFMA16(ab, wb0, acc[m], 0, 0, 0);
                        acc[m] = MFMA16(ab, wb1, acc[m], 0, 0, 0);
                        acc[m] = MFMA16(ab, wb2, acc[m], 0, 0, 0);
                    }
                }
            }
            // exo region: A = xu feats 0..31 (16..31 zero), B rows 64..95
            {
                const int f = lq * 8;
                bf16x8 wb0 = *(const bf16x8*)(Wn + 0 * W1_SPLIT + n1 * 96 + 64 + f);
                bf16x8 wb1 = *(const bf16x8*)(Wn + 1 * W1_SPLIT + n1 * 96 + 64 + f);
                bf16x8 wb2 = *(const bf16x8*)(Wn + 2 * W1_SPLIT + n1 * 96 + 64 + f);
                #pragma unroll
                for (int m = 0; m < 4; ++m) {
                    const int e = m * 16 + lr;
                    bf16x8 a0 = *(const bf16x8*)&xu[0][e][f];
                    bf16x8 a1 = *(const bf16x8*)&xu[1][e][f];
                    bf16x8 a2 = *(const bf16x8*)&xu[2][e][f];
                    acc[m] = MFMA16(a0, wb0, acc[m], 0, 0, 0);
                    acc[m] = MFMA16(a0, wb1, acc[m], 0, 0, 0);
                    acc[m] = MFMA16(a0, wb2, acc[m], 0, 0, 0);
                    acc[m] = MFMA16(a1, wb0, acc[m], 0, 0, 0);
                    acc[m] = MFMA16(a1, wb1, acc[m], 0, 0, 0);
                    acc[m] = MFMA16(a1, wb2, acc[m], 0, 0, 0);
                    acc[m] = MFMA16(a2, wb0, acc[m], 0, 0, 0);
                    acc[m] = MFMA16(a2, wb1, acc[m], 0, 0, 0);
                }
            }
            const float b1 = (i < 4) ? b_r1[i * 64 + n1] : b_i1[(i - 4) * 64 + n1];
            #pragma unroll
            for (int m = 0; m < 4; ++m) {
                #pragma unroll
                for (int r = 0; r < 4; ++r) {
                    const int e = m * 16 + lq * 4 + r;
                    float v = fmaxf(acc[m][r] + b1, 0.0f);
                    unsigned short sh, sm, sl;
                    split3(v, sh, sm, sl);
                    h1s[0][e][n1] = sh; h1s[1][e][n1] = sm; h1s[2][e][n1] = sl;
                }
            }
        }
        __syncthreads();

        // ======== L2: wave = N-tile, K = 64 ========
        {
            #pragma unroll
            for (int m = 0; m < 4; ++m) acc[m] = (f32x4){0,0,0,0};
            const unsigned short* W2 = Wn + W2_OFF;
            #pragma unroll
            for (int k0 = 0; k0 < 64; k0 += 32) {
                const int f = k0 + lq * 8;
                bf16x8 wb0 = *(const bf16x8*)(W2 + 0 * W2_SPLIT + n1 * 64 + f);
                bf16x8 wb1 = *(const bf16x8*)(W2 + 1 * W2_SPLIT + n1 * 64 + f);
                bf16x8 wb2 = *(const bf16x8*)(W2 + 2 * W2_SPLIT + n1 * 64 + f);
                #pragma unroll
                for (int m = 0; m < 4; ++m) {
                    const int e = m * 16 + lr;
                    bf16x8 a0 = *(const bf16x8*)&h1s[0][e][f];
                    bf16x8 a1 = *(const bf16x8*)&h1s[1][e][f];
                    bf16x8 a2 = *(const bf16x8*)&h1s[2][e][f];
                    acc[m] = MFMA16(a0, wb0, acc[m], 0, 0, 0);
                    acc[m] = MFMA16(a0, wb1, acc[m], 0, 0, 0);
                    acc[m] = MFMA16(a0, wb2, acc[m], 0, 0, 0);
                    acc[m] = MFMA16(a1, wb0, acc[m], 0, 0, 0);
                    acc[m] = MFMA16(a1, wb1, acc[m], 0, 0, 0);
                    acc[m] = MFMA16(a1, wb2, acc[m], 0, 0, 0);
                    acc[m] = MFMA16(a2, wb0, acc[m], 0, 0, 0);
                    acc[m] = MFMA16(a2, wb1, acc[m], 0, 0, 0);
                }
            }
            const float b2 = (i < 4) ? b_r2[i * 64 + n1] : b_i2[(i - 4) * 64 + n1];
            #pragma unroll
            for (int m = 0; m < 4; ++m) {
                #pragma unroll
                for (int r = 0; r < 4; ++r) {
                    const int e = m * 16 + lq * 4 + r;
                    float v = fmaxf(acc[m][r] + b2, 0.0f);
                    unsigned short sh, sm, sl;
                    split3(v, sh, sm, sl);
                    h2s[0][e][n1] = sh; h2s[1][e][n1] = sm; h2s[2][e][n1] = sl;
                }
            }
        }
        __syncthreads();

        // ======== L3: wave = M-tile (elems 16w..16w+15), N = 16 ========
        {
            f32x4 c3 = {0,0,0,0};
            const unsigned short* W3 = Wn + W3_OFF;
            #pragma unroll
            for (int k0 = 0; k0 < 64; k0 += 32) {
                const int f = k0 + lq * 8;
                bf16x8 wb0 = *(const bf16x8*)(W3 + 0 * W3_SPLIT + lr * 64 + f);
                bf16x8 wb1 = *(const bf16x8*)(W3 + 1 * W3_SPLIT + lr * 64 + f);
                bf16x8 wb2 = *(const bf16x8*)(W3 + 2 * W3_SPLIT + lr * 64 + f);
                const int e = 16 * w + lr;
                bf16x8 a0 = *(const bf16x8*)&h2s[0][e][f];
                bf16x8 a1 = *(const bf16x8*)&h2s[1][e][f];
                bf16x8 a2 = *(const bf16x8*)&h2s[2][e][f];
                c3 = MFMA16(a0, wb0, c3, 0, 0, 0);
                c3 = MFMA16(a0, wb1, c3, 0, 0, 0);
                c3 = MFMA16(a0, wb2, c3, 0, 0, 0);
                c3 = MFMA16(a1, wb0, c3, 0, 0, 0);
                c3 = MFMA16(a1, wb1, c3, 0, 0, 0);
                c3 = MFMA16(a1, wb2, c3, 0, 0, 0);
                c3 = MFMA16(a2, wb0, c3, 0, 0, 0);
                c3 = MFMA16(a2, wb1, c3, 0, 0, 0);
            }
            const float b3 = (i < 4) ? b_r3[i * 16 + lr] : b_i3[(i - 4) * 16 + lr];
            const int slot = i & 3;
            #pragma unroll
            for (int r = 0; r < 4; ++r) {
                const int e = 16 * w + lq * 4 + r;
                float v = c3[r] + b3;
                out[(eg + e) * 512 + i * 16 + lr] = v;
                ring[slot][e][lr] = (v > 0.5f) ? (unsigned short)0x3F80 : (unsigned short)0;
            }
        }
        // loop-top __syncthreads protects ring/xu/h for next node
    }
}

extern "C" void kernel_launch(void* const* d_in, const int* in_sizes, int n_in,
                              void* d_out, int out_size, void* d_ws, size_t ws_size,
                              hipStream_t stream) {
    const float* u    = (const float*)d_in[0];
    const float* w_r1 = (const float*)d_in[1];
    const float* b_r1 = (const float*)d_in[2];
    const float* w_r2 = (const float*)d_in[3];
    const float* b_r2 = (const float*)d_in[4];
    const float* w_r3 = (const float*)d_in[5];
    const float* b_r3 = (const float*)d_in[6];
    const float* w_i1 = (const float*)d_in[7];
    const float* b_i1 = (const float*)d_in[8];
    const float* w_i2 = (const float*)d_in[9];
    const float* b_i2 = (const float*)d_in[10];
    const float* w_i3 = (const float*)d_in[11];
    const float* b_i3 = (const float*)d_in[12];
    float* out = (float*)d_out;
    unsigned short* ws = (unsigned short*)d_ws;

    prep_weights<<<dim3((32 * PER_NODE_ITEMS) / 256), dim3(256), 0, stream>>>(
        w_r1, w_r2, w_r3, w_i1, w_i2, w_i3, ws);

    ncm_mfma<<<dim3(512), dim3(256), 0, stream>>>(
        u, ws, b_r1, b_r2, b_r3, b_i1, b_i2, b_i3, out);
}